// Round 13
// baseline (302.313 us; speedup 1.0000x reference)
//
#include <hip/hip_runtime.h>

#define D 128
#define BSH 8                    // bucket = dst >> BSH (256 nodes per bucket)
#define BNODES (1 << BSH)
#define NCHUNK 512               // edge chunks; grid of place/hist kernels
#define MAXB 512                 // LDS bucket-array capacity (NBKT <= 512, N <= 131072)

typedef __attribute__((ext_vector_type(8))) __bf16 bf16x8;
typedef __attribute__((ext_vector_type(4))) float f32x4;

__device__ __forceinline__ unsigned short f2bf(float f) {
    unsigned int u = __float_as_uint(f);
    u += 0x7fffu + ((u >> 16) & 1u);  // round-to-nearest-even
    return (unsigned short)(u >> 16);
}
// bf16 pair packed in u32 (lo = even feature, hi = odd feature)
__device__ __forceinline__ float lo_f(unsigned u) { return __uint_as_float(u << 16); }
__device__ __forceinline__ float hi_f(unsigned u) { return __uint_as_float(u & 0xffff0000u); }

// ---------------- CSR build: contention-free counting sort ----------------
// pairs layout: (dstLocal<<24) | src   (needs N < 2^24, BNODES <= 256)

// blocks [0,NCHUNK): chunk c -> LDS bucket histogram -> cnts[b][c], plus
//   per-node degree via global atomics (cnt must be pre-zeroed).
// blocks [NCHUNK, NCHUNK+128): W1/W2 f32 -> Wt bf16 transposed (folded k_wcvt).
__global__ __launch_bounds__(256) void k_histc(const int* __restrict__ dst,
                                               int* __restrict__ cnt,
                                               int* __restrict__ cnts,
                                               int E, int nbkt, int chunk,
                                               const float* __restrict__ W1,
                                               const float* __restrict__ W2,
                                               unsigned short* __restrict__ Wt1,
                                               unsigned short* __restrict__ Wt2) {
    int c = blockIdx.x;
    int t = threadIdx.x;
    if (c >= NCHUNK) {  // folded weight transpose/convert
        int idx = (c - NCHUNK) * 256 + t;  // 0 .. 32767
        const float* W = (idx < 16384) ? W1 : W2;
        unsigned short* Wt = (idx < 16384) ? Wt1 : Wt2;
        int i = idx & 16383;
        int cc = i >> 7, k = i & 127;
        Wt[(size_t)cc * 128 + k] = f2bf(W[(size_t)k * 128 + cc]);
        return;
    }
    __shared__ int hist[MAXB];
    for (int i = t; i < nbkt; i += 256) hist[i] = 0;
    __syncthreads();
    int e0 = c * chunk, e1 = min(e0 + chunk, E);
    for (int e = e0 + t; e < e1; e += 256) {
        int d = dst[e];
        atomicAdd(&cnt[d], 1);
        atomicAdd(&hist[d >> BSH], 1);
    }
    __syncthreads();
    for (int i = t; i < nbkt; i += 256) cnts[(size_t)i * NCHUNK + c] = hist[i];
}

// blocks [0,nscan): one wave per bucket, exclusive scan over NCHUNK chunk
//   counts (in place); bucket total -> btot[b].
// blocks [nscan, ...): dinv[i] = rsqrt(cnt[i]+1) (folded k_dinv).
__global__ __launch_bounds__(256) void k_chunksum(int* __restrict__ cnts,
                                                  int* __restrict__ btot,
                                                  const int* __restrict__ cnt,
                                                  float* __restrict__ dinv,
                                                  int nbkt, int nscan, int N) {
    int bid = blockIdx.x;
    int t = threadIdx.x;
    if (bid >= nscan) {  // folded dinv
        int i = (bid - nscan) * 256 + t;
        if (i < N) dinv[i] = rsqrtf((float)cnt[i] + 1.0f);  // +1 self-loop
        return;
    }
    int b = bid * 4 + (t >> 6);
    if (b >= nbkt) return;
    int l = t & 63;
    int carry = 0;
    for (int g = 0; g < NCHUNK; g += 64) {
        int v = cnts[(size_t)b * NCHUNK + g + l];
        int x = v;
#pragma unroll
        for (int off = 1; off < 64; off <<= 1) {
            int u = __shfl_up(x, off);
            if (l >= off) x += u;
        }
        cnts[(size_t)b * NCHUNK + g + l] = carry + x - v;  // exclusive
        carry += __shfl(x, 63);
    }
    if (l == 0) btot[b] = carry;
}

// one block: exclusive scan of bucket totals -> bbase[0..nbkt] (bbase[nbkt] = E)
__global__ __launch_bounds__(MAXB) void k_bktscan(const int* __restrict__ btot,
                                                  int* __restrict__ bbase, int nbkt) {
    __shared__ int s[MAXB];
    int t = threadIdx.x;
    int v = (t < nbkt) ? btot[t] : 0;
    s[t] = v;
    __syncthreads();
    for (int off = 1; off < MAXB; off <<= 1) {
        int u = (t >= off) ? s[t - off] : 0;
        __syncthreads();
        s[t] += u;
        __syncthreads();
    }
    if (t < nbkt) bbase[t + 1] = s[t];
    if (t == 0) bbase[0] = 0;
}

// chunk c: place packed pairs at precomputed per-(chunk,bucket) offsets;
// cursors advance via LDS atomics only.
__global__ __launch_bounds__(256) void k_place(const int* __restrict__ src,
                                               const int* __restrict__ dst,
                                               const int* __restrict__ cnts,
                                               const int* __restrict__ bbase,
                                               unsigned* __restrict__ pairs,
                                               int E, int nbkt, int chunk) {
    __shared__ int cur[MAXB];
    int c = blockIdx.x;
    int t = threadIdx.x;
    for (int i = t; i < nbkt; i += 256)
        cur[i] = bbase[i] + cnts[(size_t)i * NCHUNK + c];
    __syncthreads();
    int e0 = c * chunk, e1 = min(e0 + chunk, E);
    for (int e = e0 + t; e < e1; e += 256) {
        int d = dst[e];
        int p = atomicAdd(&cur[d >> BSH], 1);
        pairs[p] = ((unsigned)(d & (BNODES - 1)) << 24) | (unsigned)src[e];
    }
}

// one block per bucket: degree read coalesced from cnt (no pairs-count pass),
// wave-shfl scan (1 barrier) -> rp + local cursors, then scatter col within
// the bucket's contiguous region.
__global__ __launch_bounds__(BNODES) void k_build(const unsigned* __restrict__ pairs,
                                                  const int* __restrict__ bbase,
                                                  const int* __restrict__ cnt,
                                                  int* __restrict__ rp,
                                                  int* __restrict__ col, int N) {
    __shared__ int lcur[BNODES];
    __shared__ int wsum[BNODES / 64];
    int b = blockIdx.x;
    int n0 = b << BSH;
    int t = threadIdx.x;
    int lane = t & 63, wid = t >> 6;
    int e0 = bbase[b], e1 = bbase[b + 1];
    int node = n0 + t;

    int deg = (node < N) ? cnt[node] : 0;
    // inclusive scan: wave-level shfl scan + cross-wave fixup
    int x = deg;
#pragma unroll
    for (int off = 1; off < 64; off <<= 1) {
        int u = __shfl_up(x, off);
        if (lane >= off) x += u;
    }
    if (lane == 63) wsum[wid] = x;
    __syncthreads();
    int wbase = 0;
#pragma unroll
    for (int i = 0; i < BNODES / 64; ++i) wbase += (i < wid) ? wsum[i] : 0;
    int rpv = e0 + wbase + x - deg;  // exclusive + bucket base
    lcur[t] = rpv;
    if (node < N) {
        rp[node] = rpv;
        if (node == N - 1) rp[N] = e1;
    }
    __syncthreads();
    for (int e = e0 + t; e < e1; e += BNODES) {
        unsigned v = pairs[e];
        int p = atomicAdd(&lcur[v >> 24], 1);
        col[p] = (int)(v & 0x00FFFFFFu);
    }
}

// ---------------- x -> bf16, pre-scaled by dinv[row] ----------------
__global__ __launch_bounds__(256) void k_cvt(const float* __restrict__ x,
                                             const float* __restrict__ dinv,
                                             unsigned short* __restrict__ y, int nchunk) {
    int g = blockIdx.x * blockDim.x + threadIdx.x;
    if (g >= nchunk) return;
    int row = g >> 5;  // 32 chunks of 4 per 128-wide row
    float s = dinv[row];
    float4 v = reinterpret_cast<const float4*>(x)[g];
    ushort4 o;
    o.x = f2bf(v.x * s);
    o.y = f2bf(v.y * s);
    o.z = f2bf(v.z * s);
    o.w = f2bf(v.w * s);
    reinterpret_cast<ushort4*>(y)[g] = o;
}

// ---------------- normalized aggregation (gather, bf16 rows) ----------------
// outp[n] (bf16 pairs) = bf16( dinv[n] * ( y[n] + sum_{e in CSR(n)} y[col[e]] ) )
// R10 measured-best shape: one wave64 per node, 2-wave (128-thr) blocks; lane
// owns a bf16 feature pair (u32); edge loop unrolled x16/x8/x4/x1. This runs
// at the beyond-L2 fabric floor (~3.5 TB/s, FETCH pinned at the compulsory
// 8-XCD x working-set = 190 MB) — instruction-side variants (x8 unroll,
// 256-thr blocks, paired 8B loads) measured equal or worse (R9/R10/R11).
__global__ __launch_bounds__(128) void k_agg(const unsigned short* __restrict__ y,
                                             unsigned* __restrict__ outp,
                                             const int* __restrict__ col,
                                             const int* __restrict__ rp,
                                             const float* __restrict__ dinv, int n) {
    int node = blockIdx.x * 2 + (threadIdx.x >> 6);
    if (node >= n) return;
    int c = threadIdx.x & 63;  // feature pair index
    const unsigned* yv = reinterpret_cast<const unsigned*>(y);

    unsigned v = yv[(size_t)node * 64 + c];  // self loop
    float a0 = lo_f(v), a1 = hi_f(v);

    int e0 = rp[node], e1 = rp[node + 1];
    int e = e0;
    for (; e + 16 <= e1; e += 16) {
        int s[16];
#pragma unroll
        for (int j = 0; j < 16; ++j) s[j] = col[e + j];
        unsigned u[16];
#pragma unroll
        for (int j = 0; j < 16; ++j) u[j] = yv[(size_t)s[j] * 64 + c];
#pragma unroll
        for (int j = 0; j < 16; ++j) { a0 += lo_f(u[j]); a1 += hi_f(u[j]); }
    }
    for (; e + 8 <= e1; e += 8) {
        int s[8];
#pragma unroll
        for (int j = 0; j < 8; ++j) s[j] = col[e + j];
        unsigned u[8];
#pragma unroll
        for (int j = 0; j < 8; ++j) u[j] = yv[(size_t)s[j] * 64 + c];
#pragma unroll
        for (int j = 0; j < 8; ++j) { a0 += lo_f(u[j]); a1 += hi_f(u[j]); }
    }
    for (; e + 4 <= e1; e += 4) {
        int s0 = col[e], s1 = col[e + 1], s2 = col[e + 2], s3 = col[e + 3];
        unsigned u0 = yv[(size_t)s0 * 64 + c];
        unsigned u1 = yv[(size_t)s1 * 64 + c];
        unsigned u2 = yv[(size_t)s2 * 64 + c];
        unsigned u3 = yv[(size_t)s3 * 64 + c];
        a0 += (lo_f(u0) + lo_f(u1)) + (lo_f(u2) + lo_f(u3));
        a1 += (hi_f(u0) + hi_f(u1)) + (hi_f(u2) + hi_f(u3));
    }
    for (; e < e1; ++e) {
        unsigned u = yv[(size_t)col[e] * 64 + c];
        a0 += lo_f(u);
        a1 += hi_f(u);
    }
    float dn = dinv[node];
    unsigned o = ((unsigned)f2bf(a1 * dn) << 16) | (unsigned)f2bf(a0 * dn);
    outp[(size_t)node * 64 + c] = o;
}

// ---------------- MFMA GEMM + bias + relu (bf16 in, f32 acc) ----------------
// OPERAND-SWAPPED: D = W^T * A^T via mfma(w_frag, a_frag). Loads are identical
// to the unswapped version (fragment patterns are symmetric); the C/D layout
// (col=lane&15, row=(lane>>4)*4+reg — HW-verified) now gives:
//   output row r = r0 + mi*16 + (lane&15)
//   output col c = nf*16 + (lane>>4)*4 + reg   -> 4 CONSECUTIVE cols per lane
// so the epilogue stores uint2 (bf16) / float4 (f32) instead of scalars.
// A/B k-ordering is consistent between operands -> any bijective k-map cancels.
template <int STORE_BF16>
__global__ __launch_bounds__(256) void k_mfma(const unsigned short* __restrict__ A,
                                              const unsigned short* __restrict__ Wt,
                                              const float* __restrict__ bias,
                                              float* __restrict__ out_f32,
                                              unsigned short* __restrict__ out_bf16,
                                              const float* __restrict__ dinv, int N) {
    int tid = threadIdx.x;
    int wv = tid >> 6, l = tid & 63;
    int lr = l & 15, lg = l >> 4;
    int r0 = blockIdx.x * 128 + wv * 32;

    f32x4 acc[2][8];
#pragma unroll
    for (int mi = 0; mi < 2; ++mi)
#pragma unroll
        for (int nf = 0; nf < 8; ++nf) acc[mi][nf] = (f32x4)(0.0f);

#pragma unroll
    for (int k0 = 0; k0 < 128; k0 += 32) {
        bf16x8 a[2];
#pragma unroll
        for (int mi = 0; mi < 2; ++mi) {
            int r = r0 + mi * 16 + lr;
            if (r >= N) r = N - 1;  // clamp: loads valid, stores guarded
            a[mi] = *reinterpret_cast<const bf16x8*>(&A[(size_t)r * 128 + k0 + lg * 8]);
        }
#pragma unroll
        for (int nf = 0; nf < 8; ++nf) {
            bf16x8 bw = *reinterpret_cast<const bf16x8*>(
                &Wt[(size_t)(nf * 16 + lr) * 128 + k0 + lg * 8]);
            acc[0][nf] = __builtin_amdgcn_mfma_f32_16x16x32_bf16(bw, a[0], acc[0][nf], 0, 0, 0);
            acc[1][nf] = __builtin_amdgcn_mfma_f32_16x16x32_bf16(bw, a[1], acc[1][nf], 0, 0, 0);
        }
    }

    float4 bv4[8];
#pragma unroll
    for (int nf = 0; nf < 8; ++nf)
        bv4[nf] = *reinterpret_cast<const float4*>(&bias[nf * 16 + lg * 4]);

#pragma unroll
    for (int mi = 0; mi < 2; ++mi) {
        int r = r0 + mi * 16 + lr;
        if (r < N) {
            float dv = 1.0f;
            if (STORE_BF16) dv = dinv[r];
#pragma unroll
            for (int nf = 0; nf < 8; ++nf) {
                float v0 = fmaxf(acc[mi][nf][0] + bv4[nf].x, 0.0f);
                float v1 = fmaxf(acc[mi][nf][1] + bv4[nf].y, 0.0f);
                float v2 = fmaxf(acc[mi][nf][2] + bv4[nf].z, 0.0f);
                float v3 = fmaxf(acc[mi][nf][3] + bv4[nf].w, 0.0f);
                if (STORE_BF16) {
                    uint2 o;
                    o.x = ((unsigned)f2bf(v1 * dv) << 16) | (unsigned)f2bf(v0 * dv);
                    o.y = ((unsigned)f2bf(v3 * dv) << 16) | (unsigned)f2bf(v2 * dv);
                    *reinterpret_cast<uint2*>(&out_bf16[(size_t)r * 128 + nf * 16 + lg * 4]) = o;
                } else {
                    *reinterpret_cast<float4*>(&out_f32[(size_t)r * 128 + nf * 16 + lg * 4]) =
                        make_float4(v0, v1, v2, v3);
                }
            }
        }
    }
}

// ---------------- launch ----------------

extern "C" void kernel_launch(void* const* d_in, const int* in_sizes, int n_in,
                              void* d_out, int out_size, void* d_ws, size_t ws_size,
                              hipStream_t stream) {
    const float* x  = (const float*)d_in[0];
    const int*   ei = (const int*)d_in[1];
    const float* W1 = (const float*)d_in[2];
    const float* b1 = (const float*)d_in[3];
    const float* W2 = (const float*)d_in[4];
    const float* b2 = (const float*)d_in[5];
    float* out = (float*)d_out;

    const int N = in_sizes[0] / D;
    const int E = in_sizes[1] / 2;
    const int* src = ei;
    const int* dst = ei + E;
    const int NBKT = (N + BNODES - 1) >> BSH;     // 391 for N=100000 (<= MAXB)
    const int CHUNK = (E + NCHUNK - 1) / NCHUNK;  // 3125 for E=1.6M

    char* w = (char*)d_ws;
    auto alloc = [&](size_t bytes) -> void* {
        void* p = (void*)w;
        w += (bytes + 255) & ~(size_t)255;
        return p;
    };
    float* dinv     = (float*)alloc((size_t)N * 4);
    int* cnt        = (int*)alloc((size_t)N * 4);
    int* rp         = (int*)alloc((size_t)(N + 1) * 4);
    int* cnts       = (int*)alloc((size_t)NBKT * NCHUNK * 4);  // ~0.8 MB
    int* btot       = (int*)alloc((size_t)NBKT * 4);
    int* bbase      = (int*)alloc((size_t)(NBKT + 1) * 4);
    unsigned* pairs = (unsigned*)alloc((size_t)E * 4);
    int* col        = (int*)alloc((size_t)E * 4);
    unsigned short* y    = (unsigned short*)alloc((size_t)N * D * 2);
    unsigned short* y2   = (unsigned short*)alloc((size_t)N * D * 2);
    unsigned short* Abuf = (unsigned short*)alloc((size_t)N * D * 2);
    unsigned short* Wt1  = (unsigned short*)alloc((size_t)D * D * 2);
    unsigned short* Wt2  = (unsigned short*)alloc((size_t)D * D * 2);

    const int nscan = (NBKT + 3) / 4;             // chunksum blocks (98)
    const int dinvblocks = (N + 255) / 256;       // 391
    const int nchunk = N * (D / 4);
    const int aggblocks = (N + 1) / 2;
    const int gemmblocks = (N + 127) / 128;

    hipMemsetAsync(cnt, 0, (size_t)N * 4, stream);
    // hist + degree count + folded weight convert
    k_histc<<<NCHUNK + 128, 256, 0, stream>>>(dst, cnt, cnts, E, NBKT, CHUNK,
                                              W1, W2, Wt1, Wt2);
    // per-bucket chunk scan + folded dinv
    k_chunksum<<<nscan + dinvblocks, 256, 0, stream>>>(cnts, btot, cnt, dinv,
                                                       NBKT, nscan, N);
    k_bktscan<<<1, MAXB, 0, stream>>>(btot, bbase, NBKT);
    k_place<<<NCHUNK, 256, 0, stream>>>(src, dst, cnts, bbase, pairs, E, NBKT, CHUNK);
    k_build<<<NBKT, BNODES, 0, stream>>>(pairs, bbase, cnt, rp, col, N);

    // layer 1: y = bf16(dinv*x); Abuf = agg(y); y2 = bf16(dinv*relu(Abuf@W1+b1))
    k_cvt<<<(nchunk + 255) / 256, 256, 0, stream>>>(x, dinv, y, nchunk);
    k_agg<<<aggblocks, 128, 0, stream>>>(y, (unsigned*)Abuf, col, rp, dinv, N);
    k_mfma<1><<<gemmblocks, 256, 0, stream>>>(Abuf, Wt1, b1, nullptr, y2, dinv, N);
    // layer 2: Abuf = agg(y2); out = relu(Abuf@W2+b2) f32
    k_agg<<<aggblocks, 128, 0, stream>>>(y2, (unsigned*)Abuf, col, rp, dinv, N);
    k_mfma<0><<<gemmblocks, 256, 0, stream>>>(Abuf, Wt2, b2, out, nullptr, dinv, N);
}

// Round 14
// 242.005 us; speedup vs baseline: 1.2492x; 1.2492x over previous
//
#include <hip/hip_runtime.h>

#define D 128
#define BSH 8                    // bucket = dst >> BSH (256 nodes per bucket)
#define BNODES (1 << BSH)
#define NCHUNK 512               // edge chunks; grid of place/hist kernels
#define MAXB 512                 // LDS bucket-array capacity (NBKT <= 512, N <= 131072)

typedef __attribute__((ext_vector_type(8))) __bf16 bf16x8;
typedef __attribute__((ext_vector_type(4))) float f32x4;

__device__ __forceinline__ unsigned short f2bf(float f) {
    unsigned int u = __float_as_uint(f);
    u += 0x7fffu + ((u >> 16) & 1u);  // round-to-nearest-even
    return (unsigned short)(u >> 16);
}
// bf16 pair packed in u32 (lo = even feature, hi = odd feature)
__device__ __forceinline__ float lo_f(unsigned u) { return __uint_as_float(u << 16); }
__device__ __forceinline__ float hi_f(unsigned u) { return __uint_as_float(u & 0xffff0000u); }

// ---------------- CSR build: contention-free counting sort ----------------
// pairs layout: (dstLocal<<24) | src   (needs N < 2^24, BNODES <= 256)
// NOTE (R13 lesson): do NOT fold a per-node global atomicAdd degree count into
// the hist pass — 1.6M random 4B atomics = 64B-line write amplification
// (~56 MB WRITE_SIZE) + latency chains = +55 µs. Degrees are derived in
// k_build from the bucket's pairs via LDS atomics instead.

__global__ __launch_bounds__(256) void k_hist(const int* __restrict__ dst,
                                              int* __restrict__ cnts,
                                              int E, int nbkt, int chunk) {
    __shared__ int hist[MAXB];
    int c = blockIdx.x;
    int t = threadIdx.x;
    for (int i = t; i < nbkt; i += 256) hist[i] = 0;
    __syncthreads();
    int e0 = c * chunk, e1 = min(e0 + chunk, E);
    for (int e = e0 + t; e < e1; e += 256) atomicAdd(&hist[dst[e] >> BSH], 1);
    __syncthreads();
    for (int i = t; i < nbkt; i += 256) cnts[(size_t)i * NCHUNK + c] = hist[i];
}

// one wave per bucket: exclusive scan over the NCHUNK chunk-counts (in place),
// bucket total -> btot[b]. cnts reads/writes are lane-coalesced.
__global__ __launch_bounds__(256) void k_chunksum(int* __restrict__ cnts,
                                                  int* __restrict__ btot, int nbkt) {
    int b = blockIdx.x * 4 + (threadIdx.x >> 6);
    if (b >= nbkt) return;
    int l = threadIdx.x & 63;
    int carry = 0;
    for (int g = 0; g < NCHUNK; g += 64) {
        int v = cnts[(size_t)b * NCHUNK + g + l];
        int x = v;
#pragma unroll
        for (int off = 1; off < 64; off <<= 1) {
            int u = __shfl_up(x, off);
            if (l >= off) x += u;
        }
        cnts[(size_t)b * NCHUNK + g + l] = carry + x - v;  // exclusive
        carry += __shfl(x, 63);
    }
    if (l == 0) btot[b] = carry;
}

// one block: exclusive scan of bucket totals -> bbase[0..nbkt] (bbase[nbkt] = E)
__global__ __launch_bounds__(MAXB) void k_bktscan(const int* __restrict__ btot,
                                                  int* __restrict__ bbase, int nbkt) {
    __shared__ int s[MAXB];
    int t = threadIdx.x;
    int v = (t < nbkt) ? btot[t] : 0;
    s[t] = v;
    __syncthreads();
    for (int off = 1; off < MAXB; off <<= 1) {
        int u = (t >= off) ? s[t - off] : 0;
        __syncthreads();
        s[t] += u;
        __syncthreads();
    }
    if (t < nbkt) bbase[t + 1] = s[t];
    if (t == 0) bbase[0] = 0;
}

// chunk c: place packed pairs at precomputed per-(chunk,bucket) offsets;
// cursors advance via LDS atomics only.
__global__ __launch_bounds__(256) void k_place(const int* __restrict__ src,
                                               const int* __restrict__ dst,
                                               const int* __restrict__ cnts,
                                               const int* __restrict__ bbase,
                                               unsigned* __restrict__ pairs,
                                               int E, int nbkt, int chunk) {
    __shared__ int cur[MAXB];
    int c = blockIdx.x;
    int t = threadIdx.x;
    for (int i = t; i < nbkt; i += 256)
        cur[i] = bbase[i] + cnts[(size_t)i * NCHUNK + c];
    __syncthreads();
    int e0 = c * chunk, e1 = min(e0 + chunk, E);
    for (int e = e0 + t; e < e1; e += 256) {
        int d = dst[e];
        int p = atomicAdd(&cur[d >> BSH], 1);
        pairs[p] = ((unsigned)(d & (BNODES - 1)) << 24) | (unsigned)src[e];
    }
}

// one block per bucket: derive per-node degree (LDS count over pairs),
// wave-shfl scan (1 barrier) -> rp + dinv + local cursors, then scatter col
// within the bucket's contiguous region.
__global__ __launch_bounds__(BNODES) void k_build(const unsigned* __restrict__ pairs,
                                                  const int* __restrict__ bbase,
                                                  int* __restrict__ rp,
                                                  float* __restrict__ dinv,
                                                  int* __restrict__ col, int N) {
    __shared__ int cntL[BNODES];
    __shared__ int lcur[BNODES];
    __shared__ int wsum[BNODES / 64];
    int b = blockIdx.x;
    int n0 = b << BSH;
    int t = threadIdx.x;
    int lane = t & 63, wid = t >> 6;
    int e0 = bbase[b], e1 = bbase[b + 1];

    cntL[t] = 0;
    __syncthreads();
    for (int e = e0 + t; e < e1; e += BNODES)
        atomicAdd(&cntL[pairs[e] >> 24], 1);
    __syncthreads();
    int deg = cntL[t];
    // inclusive scan: wave-level shfl scan + cross-wave fixup
    int x = deg;
#pragma unroll
    for (int off = 1; off < 64; off <<= 1) {
        int u = __shfl_up(x, off);
        if (lane >= off) x += u;
    }
    if (lane == 63) wsum[wid] = x;
    __syncthreads();
    int wbase = 0;
#pragma unroll
    for (int i = 0; i < BNODES / 64; ++i) wbase += (i < wid) ? wsum[i] : 0;
    int rpv = e0 + wbase + x - deg;  // exclusive + bucket base
    lcur[t] = rpv;
    int node = n0 + t;
    if (node < N) {
        rp[node] = rpv;
        dinv[node] = rsqrtf((float)deg + 1.0f);  // +1 self-loop
        if (node == N - 1) rp[N] = e1;
    }
    __syncthreads();
    for (int e = e0 + t; e < e1; e += BNODES) {
        unsigned v = pairs[e];
        int p = atomicAdd(&lcur[v >> 24], 1);
        col[p] = (int)(v & 0x00FFFFFFu);
    }
}

// ---------------- x -> bf16, pre-scaled by dinv[row] ----------------
__global__ __launch_bounds__(256) void k_cvt(const float* __restrict__ x,
                                             const float* __restrict__ dinv,
                                             unsigned short* __restrict__ y, int nchunk) {
    int g = blockIdx.x * blockDim.x + threadIdx.x;
    if (g >= nchunk) return;
    int row = g >> 5;  // 32 chunks of 4 per 128-wide row
    float s = dinv[row];
    float4 v = reinterpret_cast<const float4*>(x)[g];
    ushort4 o;
    o.x = f2bf(v.x * s);
    o.y = f2bf(v.y * s);
    o.z = f2bf(v.z * s);
    o.w = f2bf(v.w * s);
    reinterpret_cast<ushort4*>(y)[g] = o;
}

// ---------------- W f32 -> Wt bf16 transposed (Wt[c][k] = W[k][c]) ----------
__global__ __launch_bounds__(256) void k_wcvt(const float* __restrict__ W1,
                                              const float* __restrict__ W2,
                                              unsigned short* __restrict__ Wt1,
                                              unsigned short* __restrict__ Wt2) {
    int idx = blockIdx.x * 256 + threadIdx.x;  // 0 .. 32767
    const float* W = (idx < 16384) ? W1 : W2;
    unsigned short* Wt = (idx < 16384) ? Wt1 : Wt2;
    int i = idx & 16383;
    int c = i >> 7, k = i & 127;
    Wt[(size_t)c * 128 + k] = f2bf(W[(size_t)k * 128 + c]);
}

// ---------------- normalized aggregation (gather, bf16 rows) ----------------
// outp[n] (bf16 pairs) = bf16( dinv[n] * ( y[n] + sum_{e in CSR(n)} y[col[e]] ) )
// R10 measured-best shape: one wave64 per node, 2-wave (128-thr) blocks; lane
// owns a bf16 feature pair (u32); edge loop unrolled x16/x8/x4/x1. This runs
// at the beyond-L2 fabric floor (~3.5 TB/s, FETCH pinned at the compulsory
// 8-XCD x working-set = 190 MB) — instruction-side variants (x8 unroll,
// 256-thr blocks, paired 8B loads) measured equal or worse (R9/R10/R11).
__global__ __launch_bounds__(128) void k_agg(const unsigned short* __restrict__ y,
                                             unsigned* __restrict__ outp,
                                             const int* __restrict__ col,
                                             const int* __restrict__ rp,
                                             const float* __restrict__ dinv, int n) {
    int node = blockIdx.x * 2 + (threadIdx.x >> 6);
    if (node >= n) return;
    int c = threadIdx.x & 63;  // feature pair index
    const unsigned* yv = reinterpret_cast<const unsigned*>(y);

    unsigned v = yv[(size_t)node * 64 + c];  // self loop
    float a0 = lo_f(v), a1 = hi_f(v);

    int e0 = rp[node], e1 = rp[node + 1];
    int e = e0;
    for (; e + 16 <= e1; e += 16) {
        int s[16];
#pragma unroll
        for (int j = 0; j < 16; ++j) s[j] = col[e + j];
        unsigned u[16];
#pragma unroll
        for (int j = 0; j < 16; ++j) u[j] = yv[(size_t)s[j] * 64 + c];
#pragma unroll
        for (int j = 0; j < 16; ++j) { a0 += lo_f(u[j]); a1 += hi_f(u[j]); }
    }
    for (; e + 8 <= e1; e += 8) {
        int s[8];
#pragma unroll
        for (int j = 0; j < 8; ++j) s[j] = col[e + j];
        unsigned u[8];
#pragma unroll
        for (int j = 0; j < 8; ++j) u[j] = yv[(size_t)s[j] * 64 + c];
#pragma unroll
        for (int j = 0; j < 8; ++j) { a0 += lo_f(u[j]); a1 += hi_f(u[j]); }
    }
    for (; e + 4 <= e1; e += 4) {
        int s0 = col[e], s1 = col[e + 1], s2 = col[e + 2], s3 = col[e + 3];
        unsigned u0 = yv[(size_t)s0 * 64 + c];
        unsigned u1 = yv[(size_t)s1 * 64 + c];
        unsigned u2 = yv[(size_t)s2 * 64 + c];
        unsigned u3 = yv[(size_t)s3 * 64 + c];
        a0 += (lo_f(u0) + lo_f(u1)) + (lo_f(u2) + lo_f(u3));
        a1 += (hi_f(u0) + hi_f(u1)) + (hi_f(u2) + hi_f(u3));
    }
    for (; e < e1; ++e) {
        unsigned u = yv[(size_t)col[e] * 64 + c];
        a0 += lo_f(u);
        a1 += hi_f(u);
    }
    float dn = dinv[node];
    unsigned o = ((unsigned)f2bf(a1 * dn) << 16) | (unsigned)f2bf(a0 * dn);
    outp[(size_t)node * 64 + c] = o;
}

// ---------------- MFMA GEMM + bias + relu (bf16 in, f32 acc) ----------------
// OPERAND-SWAPPED: D = W^T * A^T via mfma(w_frag, a_frag). Loads are identical
// to the unswapped version (fragment patterns are symmetric); the C/D layout
// (col=lane&15, row=(lane>>4)*4+reg — HW-verified) now gives:
//   output row r = r0 + mi*16 + (lane&15)
//   output col c = nf*16 + (lane>>4)*4 + reg   -> 4 CONSECUTIVE cols per lane
// so the epilogue stores uint2 (bf16) / float4 (f32) instead of scalars.
// A/B k-ordering is consistent between operands -> any bijective k-map cancels.
template <int STORE_BF16>
__global__ __launch_bounds__(256) void k_mfma(const unsigned short* __restrict__ A,
                                              const unsigned short* __restrict__ Wt,
                                              const float* __restrict__ bias,
                                              float* __restrict__ out_f32,
                                              unsigned short* __restrict__ out_bf16,
                                              const float* __restrict__ dinv, int N) {
    int tid = threadIdx.x;
    int wv = tid >> 6, l = tid & 63;
    int lr = l & 15, lg = l >> 4;
    int r0 = blockIdx.x * 128 + wv * 32;

    f32x4 acc[2][8];
#pragma unroll
    for (int mi = 0; mi < 2; ++mi)
#pragma unroll
        for (int nf = 0; nf < 8; ++nf) acc[mi][nf] = (f32x4)(0.0f);

#pragma unroll
    for (int k0 = 0; k0 < 128; k0 += 32) {
        bf16x8 a[2];
#pragma unroll
        for (int mi = 0; mi < 2; ++mi) {
            int r = r0 + mi * 16 + lr;
            if (r >= N) r = N - 1;  // clamp: loads valid, stores guarded
            a[mi] = *reinterpret_cast<const bf16x8*>(&A[(size_t)r * 128 + k0 + lg * 8]);
        }
#pragma unroll
        for (int nf = 0; nf < 8; ++nf) {
            bf16x8 bw = *reinterpret_cast<const bf16x8*>(
                &Wt[(size_t)(nf * 16 + lr) * 128 + k0 + lg * 8]);
            acc[0][nf] = __builtin_amdgcn_mfma_f32_16x16x32_bf16(bw, a[0], acc[0][nf], 0, 0, 0);
            acc[1][nf] = __builtin_amdgcn_mfma_f32_16x16x32_bf16(bw, a[1], acc[1][nf], 0, 0, 0);
        }
    }

    float4 bv4[8];
#pragma unroll
    for (int nf = 0; nf < 8; ++nf)
        bv4[nf] = *reinterpret_cast<const float4*>(&bias[nf * 16 + lg * 4]);

#pragma unroll
    for (int mi = 0; mi < 2; ++mi) {
        int r = r0 + mi * 16 + lr;
        if (r < N) {
            float dv = 1.0f;
            if (STORE_BF16) dv = dinv[r];
#pragma unroll
            for (int nf = 0; nf < 8; ++nf) {
                float v0 = fmaxf(acc[mi][nf][0] + bv4[nf].x, 0.0f);
                float v1 = fmaxf(acc[mi][nf][1] + bv4[nf].y, 0.0f);
                float v2 = fmaxf(acc[mi][nf][2] + bv4[nf].z, 0.0f);
                float v3 = fmaxf(acc[mi][nf][3] + bv4[nf].w, 0.0f);
                if (STORE_BF16) {
                    uint2 o;
                    o.x = ((unsigned)f2bf(v1 * dv) << 16) | (unsigned)f2bf(v0 * dv);
                    o.y = ((unsigned)f2bf(v3 * dv) << 16) | (unsigned)f2bf(v2 * dv);
                    *reinterpret_cast<uint2*>(&out_bf16[(size_t)r * 128 + nf * 16 + lg * 4]) = o;
                } else {
                    *reinterpret_cast<float4*>(&out_f32[(size_t)r * 128 + nf * 16 + lg * 4]) =
                        make_float4(v0, v1, v2, v3);
                }
            }
        }
    }
}

// ---------------- launch ----------------

extern "C" void kernel_launch(void* const* d_in, const int* in_sizes, int n_in,
                              void* d_out, int out_size, void* d_ws, size_t ws_size,
                              hipStream_t stream) {
    const float* x  = (const float*)d_in[0];
    const int*   ei = (const int*)d_in[1];
    const float* W1 = (const float*)d_in[2];
    const float* b1 = (const float*)d_in[3];
    const float* W2 = (const float*)d_in[4];
    const float* b2 = (const float*)d_in[5];
    float* out = (float*)d_out;

    const int N = in_sizes[0] / D;
    const int E = in_sizes[1] / 2;
    const int* src = ei;
    const int* dst = ei + E;
    const int NBKT = (N + BNODES - 1) >> BSH;     // 391 for N=100000 (<= MAXB)
    const int CHUNK = (E + NCHUNK - 1) / NCHUNK;  // 3125 for E=1.6M

    char* w = (char*)d_ws;
    auto alloc = [&](size_t bytes) -> void* {
        void* p = (void*)w;
        w += (bytes + 255) & ~(size_t)255;
        return p;
    };
    float* dinv     = (float*)alloc((size_t)N * 4);
    int* rp         = (int*)alloc((size_t)(N + 1) * 4);
    int* cnts       = (int*)alloc((size_t)NBKT * NCHUNK * 4);  // ~0.8 MB
    int* btot       = (int*)alloc((size_t)NBKT * 4);
    int* bbase      = (int*)alloc((size_t)(NBKT + 1) * 4);
    unsigned* pairs = (unsigned*)alloc((size_t)E * 4);
    int* col        = (int*)alloc((size_t)E * 4);
    unsigned short* y    = (unsigned short*)alloc((size_t)N * D * 2);
    unsigned short* y2   = (unsigned short*)alloc((size_t)N * D * 2);
    unsigned short* Abuf = (unsigned short*)alloc((size_t)N * D * 2);
    unsigned short* Wt1  = (unsigned short*)alloc((size_t)D * D * 2);
    unsigned short* Wt2  = (unsigned short*)alloc((size_t)D * D * 2);

    k_hist<<<NCHUNK, 256, 0, stream>>>(dst, cnts, E, NBKT, CHUNK);
    k_chunksum<<<(NBKT + 3) / 4, 256, 0, stream>>>(cnts, btot, NBKT);
    k_bktscan<<<1, MAXB, 0, stream>>>(btot, bbase, NBKT);
    k_place<<<NCHUNK, 256, 0, stream>>>(src, dst, cnts, bbase, pairs, E, NBKT, CHUNK);
    k_build<<<NBKT, BNODES, 0, stream>>>(pairs, bbase, rp, dinv, col, N);
    k_wcvt<<<128, 256, 0, stream>>>(W1, W2, Wt1, Wt2);

    const int nchunk = N * (D / 4);
    const int aggblocks = (N + 1) / 2;
    const int gemmblocks = (N + 127) / 128;

    // layer 1: y = bf16(dinv*x); Abuf = agg(y); y2 = bf16(dinv*relu(Abuf@W1+b1))
    k_cvt<<<(nchunk + 255) / 256, 256, 0, stream>>>(x, dinv, y, nchunk);
    k_agg<<<aggblocks, 128, 0, stream>>>(y, (unsigned*)Abuf, col, rp, dinv, N);
    k_mfma<1><<<gemmblocks, 256, 0, stream>>>(Abuf, Wt1, b1, nullptr, y2, dinv, N);
    // layer 2: Abuf = agg(y2); out = relu(Abuf@W2+b2) f32
    k_agg<<<aggblocks, 128, 0, stream>>>(y2, (unsigned*)Abuf, col, rp, dinv, N);
    k_mfma<0><<<gemmblocks, 256, 0, stream>>>(Abuf, Wt2, b2, out, nullptr, dinv, N);
}